// Round 17
// baseline (85.789 us; speedup 1.0000x reference)
//
#include <hip/hip_runtime.h>

#define NN 50000
#define NE 800000
#define FIN 128
#define NH 4
#define OPH 32
#define FOUT 128
#define NSLOPE 0.2f
#define NGB ((NN + 63) / 64)       // 782 GEMM tiles (64 nodes each)
#define BCOLS 144                  // 128 Wh + 4 e_l + 4 e_r + 8 pad
#define LDA 136                    // LDS A row stride (ushorts)
// two-level partition
#define BSH 5                      // 32 dsts per bucket
#define BUKSZ 32
#define NBUK ((NN + BUKSZ - 1) >> BSH)   // 1563 buckets
#define CHUNK 4096                 // edges per chunk
#define NPB1 ((NE + CHUNK - 1) / CHUNK)  // 196 chunks
#define RSPLIT 4                   // bucket-range sub-blocks per chunk
#define RSPAN ((NBUK + RSPLIT - 1) / RSPLIT)  // 391 buckets per range
#define NPARTB (NPB1 * RSPLIT)     // 784 partition blocks
#define SLOTP 16                   // words per cell: [count | 15 entries]
#define SLOTQ 15                   // capacity (lam 2.62 -> P(>=15)~1.7e-8)
#define SLOTS 64                   // final per-dst list cap
#define GRID1 (2 * NPARTB)         // 1568: even = GEMM, odd = part

typedef __attribute__((ext_vector_type(8))) short short8v;
typedef __attribute__((ext_vector_type(4))) float f32x4;

// round-to-nearest-even f32 -> bf16 (finite values)
static __device__ __forceinline__ unsigned short f2bf(float f) {
  unsigned int u = __float_as_uint(f);
  u += 0x7fffu + ((u >> 16) & 1u);
  return (unsigned short)(u >> 16);
}

// ---------------------------------------------------------------------------
// Prep: emit B in MFMA fragment order (R16-proven):
//   Btf[((ct*4+s)*64 + l)*8 + j] = B(row=ct*16+(l&15), k=s*32+(l>>4)*8+j)
// ---------------------------------------------------------------------------
__global__ __launch_bounds__(128) void k_prep(
    const float* __restrict__ W, const float* __restrict__ a_l,
    const float* __restrict__ a_r, unsigned short* __restrict__ Btf) {
  const int c = blockIdx.x;    // row 0..143
  const int f = threadIdx.x;   // k 0..127
  unsigned short v = 0;
  if (c < 128) {
    const int h = c >> 5, o = c & 31;
    v = f2bf(W[h * (FIN * OPH) + f * OPH + o]);
  } else if (c < 136) {
    const int j = c - 128;
    const int h = j & 3;
    const float* __restrict__ av = (j < 4) ? a_l : a_r;
    float s = 0.f;
    for (int o = 0; o < 32; ++o)
      s += W[h * (FIN * OPH) + f * OPH + o] * av[h * OPH + o];
    v = f2bf(s);
  }
  const int ct = c >> 4, lr = c & 15;
  const int s = f >> 5, rem = f & 31, lk = rem >> 3, j = rem & 7;
  const int l = lr + 16 * lk;
  Btf[(((size_t)ct * 4 + s) * 64 + l) * 8 + j] = v;
}

// ---------------------------------------------------------------------------
// Fused MFMA projection + bucket-range-split partition.
// even bid -> GEMM tile (R16 fragment-B code, proven).
// odd  bid -> partition sub-block: (part = pidx>>2, range r = pidx&3) owns
//   buckets [r*391, ...): 16 edge-load iterations, ~25% lanes pass the range
//   filter -> LDS ticket (cntl = 1.6 KB only!) -> scattered cell store.
//   784 short, small part blocks co-resident with 784 GEMM blocks.
// ---------------------------------------------------------------------------
__global__ __launch_bounds__(256) void k_gemm_part(
    const float* __restrict__ x, const unsigned short* __restrict__ Btf,
    const int* __restrict__ src, const int* __restrict__ dst,
    unsigned int* __restrict__ ebuf,
    unsigned short* __restrict__ WhU, float* __restrict__ e_l4,
    float* __restrict__ e_r4) {
  __shared__ union U {
    unsigned short As[64 * LDA];            // GEMM role (17408 B)
    int cntl[RSPAN + 1];                    // part role (1568 B)
  } sh;
  const int t = threadIdx.x;
  const int bid = blockIdx.x;

  if (bid & 1) {                            // ---- partition role ----
    const int pidx = bid >> 1;              // 0..783
    const int part = pidx >> 2;             // 0..195
    const int r = pidx & 3;
    const int lob = r * RSPAN;
    const int hib = min(lob + RSPAN, NBUK);
    const int base = part * CHUNK;
    for (int b = t; b < RSPAN; b += 256) sh.cntl[b] = 0;
    __syncthreads();
    unsigned int* __restrict__ myreg = ebuf + (size_t)part * NBUK * SLOTP;
#pragma unroll
    for (int k = 0; k < CHUNK / 256; ++k) {   // 16 iterations
      const int i = base + k * 256 + t;
      if (i < NE) {
        const int d = dst[i];
        const int b = d >> BSH;
        if (b >= lob && b < hib) {
          const int lp = atomicAdd(&sh.cntl[b - lob], 1);
          if (lp < SLOTQ)
            myreg[b * SLOTP + 1 + lp] =
                ((unsigned int)(d & (BUKSZ - 1)) << 16) | (unsigned int)src[i];
        }
      }
    }
    __syncthreads();
    for (int b = lob + t; b < hib; b += 256)
      myreg[b * SLOTP] = (unsigned int)min(sh.cntl[b - lob], SLOTQ);
    return;
  }

  // ---- GEMM role (R16 fragment-B, proven) ----
  const int g = bid >> 1;                   // 0..783
  if (g >= NGB) return;
  const int m0 = g * 64;

#pragma unroll
  for (int i = 0; i < 8; ++i) {
    const int fidx = t + i * 256;           // float4 index in the 64x128 tile
    const int node = fidx >> 5;
    const int fg = fidx & 31;               // f = fg*4
    const int n = m0 + node;
    float4 v = make_float4(0.f, 0.f, 0.f, 0.f);
    if (n < NN) v = *(const float4*)(x + (size_t)n * FIN + fg * 4);
    ushort4 pk;
    pk.x = f2bf(v.x); pk.y = f2bf(v.y); pk.z = f2bf(v.z); pk.w = f2bf(v.w);
    *(ushort4*)&sh.As[node * LDA + fg * 4] = pk;
  }
  __syncthreads();

  const int w = t >> 6;                     // wave 0..3 -> rows w*16..+16
  const int l = t & 63;
  const int lr = l & 15;                    // A row / B col / D col
  const int lk = l >> 4;                    // k-chunk (8 elems each)

  short8v a_frag[4];
#pragma unroll
  for (int kk = 0; kk < 4; ++kk)
    a_frag[kk] = *(const short8v*)&sh.As[(w * 16 + lr) * LDA + kk * 32 + lk * 8];

  f32x4 acc[9];
#pragma unroll
  for (int ct = 0; ct < 9; ++ct) acc[ct] = (f32x4){0.f, 0.f, 0.f, 0.f};

#pragma unroll
  for (int ct = 0; ct < 9; ++ct) {
    const unsigned short* __restrict__ Bp = Btf + ((size_t)ct * 4) * 512 + l * 8;
    short8v b0 = *(const short8v*)(Bp);
    short8v b1 = *(const short8v*)(Bp + 512);
    short8v b2 = *(const short8v*)(Bp + 1024);
    short8v b3 = *(const short8v*)(Bp + 1536);
    acc[ct] = __builtin_amdgcn_mfma_f32_16x16x32_bf16(a_frag[0], b0, acc[ct], 0, 0, 0);
    acc[ct] = __builtin_amdgcn_mfma_f32_16x16x32_bf16(a_frag[1], b1, acc[ct], 0, 0, 0);
    acc[ct] = __builtin_amdgcn_mfma_f32_16x16x32_bf16(a_frag[2], b2, acc[ct], 0, 0, 0);
    acc[ct] = __builtin_amdgcn_mfma_f32_16x16x32_bf16(a_frag[3], b3, acc[ct], 0, 0, 0);
  }

  // epilogue: D col = lr, row = lk*4 + reg (verified m89 mapping)
#pragma unroll
  for (int ct = 0; ct < 9; ++ct) {
#pragma unroll
    for (int reg = 0; reg < 4; ++reg) {
      const int n = m0 + w * 16 + lk * 4 + reg;
      if (n >= NN) continue;
      const float v = acc[ct][reg];
      if (ct < 8) {
        WhU[(size_t)n * FOUT + ct * 16 + lr] = f2bf(v);
      } else if (lr < 4) {
        e_l4[n * NH + lr] = v;
      } else if (lr < 8) {
        e_r4[n * NH + (lr - 4)] = v;
      }
    }
  }
}

// ---------------------------------------------------------------------------
// Fused list-build + aggregation (R15's 196-part variant, proven).
// ---------------------------------------------------------------------------
__global__ __launch_bounds__(256) void k_lists_agg(
    const unsigned int* __restrict__ ebuf,
    const float* __restrict__ e_l4, const float* __restrict__ e_r4,
    const unsigned int* __restrict__ Whh, float* __restrict__ out) {
  __shared__ int lists[BUKSZ][SLOTS];   // 8 KB
  __shared__ int cur[BUKSZ];
  __shared__ int pfx[256];              // inclusive scan of 196 counts
  __shared__ float exs[4][64][4];       // 4 KB

  const int b = blockIdx.x;
  const int t = threadIdx.x;
  const int w = t >> 6;
  const int lane = t & 63;

  if (t < BUKSZ) cur[t] = 0;
  pfx[t] = (t < NPB1) ? (int)ebuf[((size_t)t * NBUK + b) * SLOTP] : 0;
  __syncthreads();

  // inclusive Hillis-Steele scan over 256
  for (int d = 1; d < 256; d <<= 1) {
    const int add = (t >= d) ? pfx[t - d] : 0;
    __syncthreads();
    pfx[t] += add;
    __syncthreads();
  }
  const int T = pfx[255];

  // ---- phase A: each thread claims one valid packed edge ----
  for (int tid = t; tid < T; tid += 256) {
    int lo = 0, hi = 255;                  // first j with pfx[j] > tid
    while (lo < hi) {
      const int mid = (lo + hi) >> 1;
      if (pfx[mid] > tid) hi = mid; else lo = mid + 1;
    }
    const int j = lo;
    const int p = tid - (j ? pfx[j - 1] : 0);
    const unsigned int v = ebuf[((size_t)j * NBUK + b) * SLOTP + 1 + p];
    const int idx = (int)(v >> 16);
    const int lp = atomicAdd(&cur[idx], 1);
    if (lp < SLOTS) lists[idx][lp] = (int)(v & 0xFFFFu);
  }
  __syncthreads();

  // ---- phase B: aggregate 8 nodes per wave ----
  const int h = lane >> 4;
#pragma unroll
  for (int nl = 0; nl < 8; ++nl) {
    const int idx = w * 8 + nl;
    const int n = (b << BSH) + idx;
    if (n >= NN) continue;
    const int deg = min(cur[idx], SLOTS);
    const float4 ern = *(const float4*)&e_r4[n * NH];

    float e0 = 0.f, e1 = 0.f, e2 = 0.f, e3 = 0.f;
    if (lane < deg) {
      const int s = lists[idx][lane];
      const float4 el = *(const float4*)&e_l4[s * NH];   // L2-resident table
      float l0 = el.x + ern.x; l0 = (l0 >= 0.f) ? l0 : NSLOPE * l0;
      float l1 = el.y + ern.y; l1 = (l1 >= 0.f) ? l1 : NSLOPE * l1;
      float l2 = el.z + ern.z; l2 = (l2 >= 0.f) ? l2 : NSLOPE * l2;
      float l3 = el.w + ern.w; l3 = (l3 >= 0.f) ? l3 : NSLOPE * l3;
      e0 = __expf(l0); e1 = __expf(l1);
      e2 = __expf(l2); e3 = __expf(l3);
    }
    *(float4*)exs[w][lane] = make_float4(e0, e1, e2, e3);
    float D0 = e0, D1 = e1, D2 = e2, D3 = e3;
#pragma unroll
    for (int mm = 32; mm >= 1; mm >>= 1) {
      D0 += __shfl_xor(D0, mm);
      D1 += __shfl_xor(D1, mm);
      D2 += __shfl_xor(D2, mm);
      D3 += __shfl_xor(D3, mm);
    }

    float acc0 = 0.f, acc1 = 0.f;
    int jl = 0;
    for (; jl + 7 < deg; jl += 8) {          // 8 independent loads in flight
      int sj[8];
#pragma unroll
      for (int u = 0; u < 8; ++u) sj[u] = lists[idx][jl + u];
      unsigned int vv[8];
#pragma unroll
      for (int u = 0; u < 8; ++u) vv[u] = Whh[(size_t)sj[u] * 64 + lane];
#pragma unroll
      for (int u = 0; u < 8; ++u) {
        const float wH = exs[w][jl + u][h];
        acc0 = fmaf(wH, __uint_as_float(vv[u] << 16), acc0);
        acc1 = fmaf(wH, __uint_as_float(vv[u] & 0xffff0000u), acc1);
      }
    }
    for (; jl < deg; ++jl) {
      const int sj = lists[idx][jl];
      const float wH = exs[w][jl][h];
      const unsigned int v = Whh[(size_t)sj * 64 + lane];
      acc0 = fmaf(wH, __uint_as_float(v << 16), acc0);
      acc1 = fmaf(wH, __uint_as_float(v & 0xffff0000u), acc1);
    }

    const float dH = (h == 0) ? D0 : (h == 1) ? D1 : (h == 2) ? D2 : D3;
    const float inv = 1.f / (dH + 1e-16f);
    *(float2*)&out[(size_t)n * FOUT + 2 * lane] =
        make_float2(acc0 * inv, acc1 * inv);
  }
}

// ---------------------------------------------------------------------------
extern "C" void kernel_launch(void* const* d_in, const int* in_sizes, int n_in,
                              void* d_out, int out_size, void* d_ws, size_t ws_size,
                              hipStream_t stream) {
  const float* x   = (const float*)d_in[0];
  const int*   ei  = (const int*)d_in[1];   // [2][E]: src = ei, dst = ei + NE
  const float* W   = (const float*)d_in[2];
  const float* a_l = (const float*)d_in[3];
  const float* a_r = (const float*)d_in[4];
  float* out = (float*)d_out;

  const int* src = ei;
  const int* dst = ei + NE;

  // workspace layout (4-byte words; every array 16B-aligned)
  unsigned int* Whh = (unsigned int*)d_ws;            // NN*64 words (12.8 MB)
  float* e_l4     = (float*)(Whh + (size_t)NN * 64);  // NN*4
  float* e_r4     = e_l4 + NN * NH;                   // NN*4
  unsigned short* Btf = (unsigned short*)(e_r4 + NN * NH); // 36 KB
  unsigned int* ebuf = (unsigned int*)(Btf + 9 * 4 * 64 * 8); // 196*1563*16 (19.6 MB)
  (void)ws_size; (void)in_sizes; (void)n_in; (void)out_size;

  k_prep<<<BCOLS, 128, 0, stream>>>(W, a_l, a_r, Btf);

  k_gemm_part<<<GRID1, 256, 0, stream>>>(
      x, Btf, src, dst, ebuf, (unsigned short*)Whh, e_l4, e_r4);

  k_lists_agg<<<NBUK, 256, 0, stream>>>(ebuf, e_l4, e_r4, Whh, out);
}

// Round 18
// 80.396 us; speedup vs baseline: 1.0671x; 1.0671x over previous
//
#include <hip/hip_runtime.h>

#define NN 50000
#define NE 800000
#define FIN 128
#define NH 4
#define OPH 32
#define FOUT 128
#define NSLOPE 0.2f
#define NGB ((NN + 63) / 64)       // 782 GEMM tiles (64 nodes each)
#define BCOLS 144                  // 128 Wh + 4 e_l + 4 e_r + 8 pad
#define LDA 136                    // LDS A row stride (ushorts)
// two-level partition
#define BSH 5                      // 32 dsts per bucket
#define BUKSZ 32
#define NBUK ((NN + BUKSZ - 1) >> BSH)   // 1563 buckets
#define CHUNK 8192                 // edges per chunk
#define NPB1 ((NE + CHUNK - 1) / CHUNK)  // 98 chunks (consumer-proven layout)
#define RSPLIT 4                   // bucket-range sub-blocks per chunk
#define RSPAN ((NBUK + RSPLIT - 1) / RSPLIT)  // 391 buckets per range
#define NPARTB (NPB1 * RSPLIT)     // 392 partition blocks
#define SLOTP 32                   // words per cell: [count | 31 entries]
#define SLOTQ 31                   // capacity (lam 5.24 -> P(>31)~1e-15)
#define SLOTS 64                   // final per-dst list cap
#define NTRIP 392                  // triples: 2 GEMM + 1 part each
#define GRID1 (3 * NTRIP)          // 1176

typedef __attribute__((ext_vector_type(8))) short short8v;
typedef __attribute__((ext_vector_type(4))) float f32x4;

// round-to-nearest-even f32 -> bf16 (finite values)
static __device__ __forceinline__ unsigned short f2bf(float f) {
  unsigned int u = __float_as_uint(f);
  u += 0x7fffu + ((u >> 16) & 1u);
  return (unsigned short)(u >> 16);
}

// ---------------------------------------------------------------------------
// Prep: emit B in MFMA fragment order (R16-proven):
//   Btf[((ct*4+s)*64 + l)*8 + j] = B(row=ct*16+(l&15), k=s*32+(l>>4)*8+j)
// ---------------------------------------------------------------------------
__global__ __launch_bounds__(128) void k_prep(
    const float* __restrict__ W, const float* __restrict__ a_l,
    const float* __restrict__ a_r, unsigned short* __restrict__ Btf) {
  const int c = blockIdx.x;    // row 0..143
  const int f = threadIdx.x;   // k 0..127
  unsigned short v = 0;
  if (c < 128) {
    const int h = c >> 5, o = c & 31;
    v = f2bf(W[h * (FIN * OPH) + f * OPH + o]);
  } else if (c < 136) {
    const int j = c - 128;
    const int h = j & 3;
    const float* __restrict__ av = (j < 4) ? a_l : a_r;
    float s = 0.f;
    for (int o = 0; o < 32; ++o)
      s += W[h * (FIN * OPH) + f * OPH + o] * av[h * OPH + o];
    v = f2bf(s);
  }
  const int ct = c >> 4, lr = c & 15;
  const int s = f >> 5, rem = f & 31, lk = rem >> 3, j = rem & 7;
  const int l = lr + 16 * lk;
  Btf[(((size_t)ct * 4 + s) * 64 + l) * 8 + j] = v;
}

// ---------------------------------------------------------------------------
// Fused MFMA projection + range-split partition into 98-part cells.
// bid%3==2 -> part sub-block: (part = pidx>>2, range r = pidx&3) owns
//   buckets [r*391, ...): 32 edge iters, ~25% lanes pass filter -> LDS
//   ticket (1.6 KB cntl) -> cell store. 392 short blocks.
// else     -> GEMM tile (R16 fragment-B code, proven).
// Cell (block-exclusive, 128B): word0 = count, words1..31 = (dstlow<<16|src).
// ---------------------------------------------------------------------------
__global__ __launch_bounds__(256) void k_gemm_part(
    const float* __restrict__ x, const unsigned short* __restrict__ Btf,
    const int* __restrict__ src, const int* __restrict__ dst,
    unsigned int* __restrict__ ebuf,
    unsigned short* __restrict__ WhU, float* __restrict__ e_l4,
    float* __restrict__ e_r4) {
  __shared__ union U {
    unsigned short As[64 * LDA];            // GEMM role (17408 B)
    int cntl[RSPAN + 1];                    // part role (1568 B)
  } sh;
  const int t = threadIdx.x;
  const int bid = blockIdx.x;

  if (bid % 3 == 2) {                       // ---- partition role ----
    const int pidx = bid / 3;               // 0..391
    const int part = pidx >> 2;             // 0..97
    const int r = pidx & 3;
    const int lob = r * RSPAN;
    const int hib = min(lob + RSPAN, NBUK);
    const int base = part * CHUNK;
    for (int b = t; b < RSPAN; b += 256) sh.cntl[b] = 0;
    __syncthreads();
    unsigned int* __restrict__ myreg = ebuf + (size_t)part * NBUK * SLOTP;
#pragma unroll
    for (int k = 0; k < CHUNK / 256; ++k) {   // 32 iterations
      const int i = base + k * 256 + t;
      if (i < NE) {
        const int d = dst[i];
        const int b = d >> BSH;
        if (b >= lob && b < hib) {
          const int lp = atomicAdd(&sh.cntl[b - lob], 1);
          if (lp < SLOTQ)
            myreg[b * SLOTP + 1 + lp] =
                ((unsigned int)(d & (BUKSZ - 1)) << 16) | (unsigned int)src[i];
        }
      }
    }
    __syncthreads();
    for (int b = lob + t; b < hib; b += 256)
      myreg[b * SLOTP] = (unsigned int)min(sh.cntl[b - lob], SLOTQ);
    return;
  }

  // ---- GEMM role (R16 fragment-B, proven) ----
  const int g = (bid / 3) * 2 + (bid % 3);  // 0..783
  if (g >= NGB) return;
  const int m0 = g * 64;

#pragma unroll
  for (int i = 0; i < 8; ++i) {
    const int fidx = t + i * 256;           // float4 index in the 64x128 tile
    const int node = fidx >> 5;
    const int fg = fidx & 31;               // f = fg*4
    const int n = m0 + node;
    float4 v = make_float4(0.f, 0.f, 0.f, 0.f);
    if (n < NN) v = *(const float4*)(x + (size_t)n * FIN + fg * 4);
    ushort4 pk;
    pk.x = f2bf(v.x); pk.y = f2bf(v.y); pk.z = f2bf(v.z); pk.w = f2bf(v.w);
    *(ushort4*)&sh.As[node * LDA + fg * 4] = pk;
  }
  __syncthreads();

  const int w = t >> 6;                     // wave 0..3 -> rows w*16..+16
  const int l = t & 63;
  const int lr = l & 15;                    // A row / B col / D col
  const int lk = l >> 4;                    // k-chunk (8 elems each)

  short8v a_frag[4];
#pragma unroll
  for (int kk = 0; kk < 4; ++kk)
    a_frag[kk] = *(const short8v*)&sh.As[(w * 16 + lr) * LDA + kk * 32 + lk * 8];

  f32x4 acc[9];
#pragma unroll
  for (int ct = 0; ct < 9; ++ct) acc[ct] = (f32x4){0.f, 0.f, 0.f, 0.f};

#pragma unroll
  for (int ct = 0; ct < 9; ++ct) {
    const unsigned short* __restrict__ Bp = Btf + ((size_t)ct * 4) * 512 + l * 8;
    short8v b0 = *(const short8v*)(Bp);
    short8v b1 = *(const short8v*)(Bp + 512);
    short8v b2 = *(const short8v*)(Bp + 1024);
    short8v b3 = *(const short8v*)(Bp + 1536);
    acc[ct] = __builtin_amdgcn_mfma_f32_16x16x32_bf16(a_frag[0], b0, acc[ct], 0, 0, 0);
    acc[ct] = __builtin_amdgcn_mfma_f32_16x16x32_bf16(a_frag[1], b1, acc[ct], 0, 0, 0);
    acc[ct] = __builtin_amdgcn_mfma_f32_16x16x32_bf16(a_frag[2], b2, acc[ct], 0, 0, 0);
    acc[ct] = __builtin_amdgcn_mfma_f32_16x16x32_bf16(a_frag[3], b3, acc[ct], 0, 0, 0);
  }

  // epilogue: D col = lr, row = lk*4 + reg (verified m89 mapping)
#pragma unroll
  for (int ct = 0; ct < 9; ++ct) {
#pragma unroll
    for (int reg = 0; reg < 4; ++reg) {
      const int n = m0 + w * 16 + lk * 4 + reg;
      if (n >= NN) continue;
      const float v = acc[ct][reg];
      if (ct < 8) {
        WhU[(size_t)n * FOUT + ct * 16 + lr] = f2bf(v);
      } else if (lr < 4) {
        e_l4[n * NH + lr] = v;
      } else if (lr < 8) {
        e_r4[n * NH + (lr - 4)] = v;
      }
    }
  }
}

// ---------------------------------------------------------------------------
// Fused list-build + aggregation (R13-proven 98-part consumer, unchanged).
// ---------------------------------------------------------------------------
__global__ __launch_bounds__(256) void k_lists_agg(
    const unsigned int* __restrict__ ebuf,
    const float* __restrict__ e_l4, const float* __restrict__ e_r4,
    const unsigned int* __restrict__ Whh, float* __restrict__ out) {
  __shared__ int lists[BUKSZ][SLOTS];   // 8 KB
  __shared__ int cur[BUKSZ];
  __shared__ int pfx[128];              // inclusive scan of 98 counts
  __shared__ float exs[4][64][4];       // 4 KB

  const int b = blockIdx.x;
  const int t = threadIdx.x;
  const int w = t >> 6;
  const int lane = t & 63;

  if (t < BUKSZ) cur[t] = 0;
  if (t < 128)
    pfx[t] = (t < NPB1)
                 ? (int)ebuf[((size_t)t * NBUK + b) * SLOTP]   // cell header
                 : 0;
  __syncthreads();

  for (int d = 1; d < 128; d <<= 1) {
    int add = 0;
    if (t < 128 && t >= d) add = pfx[t - d];
    __syncthreads();
    if (t < 128) pfx[t] += add;
    __syncthreads();
  }
  const int T = pfx[127];

  // ---- phase A: each thread claims one valid packed edge ----
  for (int tid = t; tid < T; tid += 256) {
    int lo = 0, hi = 127;                  // first j with pfx[j] > tid
    while (lo < hi) {
      const int mid = (lo + hi) >> 1;
      if (pfx[mid] > tid) hi = mid; else lo = mid + 1;
    }
    const int j = lo;
    const int p = tid - (j ? pfx[j - 1] : 0);
    const unsigned int v = ebuf[((size_t)j * NBUK + b) * SLOTP + 1 + p];
    const int idx = (int)(v >> 16);
    const int lp = atomicAdd(&cur[idx], 1);
    if (lp < SLOTS) lists[idx][lp] = (int)(v & 0xFFFFu);
  }
  __syncthreads();

  // ---- phase B: aggregate 8 nodes per wave ----
  const int h = lane >> 4;
#pragma unroll
  for (int nl = 0; nl < 8; ++nl) {
    const int idx = w * 8 + nl;
    const int n = (b << BSH) + idx;
    if (n >= NN) continue;
    const int deg = min(cur[idx], SLOTS);
    const float4 ern = *(const float4*)&e_r4[n * NH];

    float e0 = 0.f, e1 = 0.f, e2 = 0.f, e3 = 0.f;
    if (lane < deg) {
      const int s = lists[idx][lane];
      const float4 el = *(const float4*)&e_l4[s * NH];   // L2-resident table
      float l0 = el.x + ern.x; l0 = (l0 >= 0.f) ? l0 : NSLOPE * l0;
      float l1 = el.y + ern.y; l1 = (l1 >= 0.f) ? l1 : NSLOPE * l1;
      float l2 = el.z + ern.z; l2 = (l2 >= 0.f) ? l2 : NSLOPE * l2;
      float l3 = el.w + ern.w; l3 = (l3 >= 0.f) ? l3 : NSLOPE * l3;
      e0 = __expf(l0); e1 = __expf(l1);
      e2 = __expf(l2); e3 = __expf(l3);
    }
    *(float4*)exs[w][lane] = make_float4(e0, e1, e2, e3);
    float D0 = e0, D1 = e1, D2 = e2, D3 = e3;
#pragma unroll
    for (int mm = 32; mm >= 1; mm >>= 1) {
      D0 += __shfl_xor(D0, mm);
      D1 += __shfl_xor(D1, mm);
      D2 += __shfl_xor(D2, mm);
      D3 += __shfl_xor(D3, mm);
    }

    float acc0 = 0.f, acc1 = 0.f;
    int jl = 0;
    for (; jl + 7 < deg; jl += 8) {          // 8 independent loads in flight
      int sj[8];
#pragma unroll
      for (int u = 0; u < 8; ++u) sj[u] = lists[idx][jl + u];
      unsigned int vv[8];
#pragma unroll
      for (int u = 0; u < 8; ++u) vv[u] = Whh[(size_t)sj[u] * 64 + lane];
#pragma unroll
      for (int u = 0; u < 8; ++u) {
        const float wH = exs[w][jl + u][h];
        acc0 = fmaf(wH, __uint_as_float(vv[u] << 16), acc0);
        acc1 = fmaf(wH, __uint_as_float(vv[u] & 0xffff0000u), acc1);
      }
    }
    for (; jl < deg; ++jl) {
      const int sj = lists[idx][jl];
      const float wH = exs[w][jl][h];
      const unsigned int v = Whh[(size_t)sj * 64 + lane];
      acc0 = fmaf(wH, __uint_as_float(v << 16), acc0);
      acc1 = fmaf(wH, __uint_as_float(v & 0xffff0000u), acc1);
    }

    const float dH = (h == 0) ? D0 : (h == 1) ? D1 : (h == 2) ? D2 : D3;
    const float inv = 1.f / (dH + 1e-16f);
    *(float2*)&out[(size_t)n * FOUT + 2 * lane] =
        make_float2(acc0 * inv, acc1 * inv);
  }
}

// ---------------------------------------------------------------------------
extern "C" void kernel_launch(void* const* d_in, const int* in_sizes, int n_in,
                              void* d_out, int out_size, void* d_ws, size_t ws_size,
                              hipStream_t stream) {
  const float* x   = (const float*)d_in[0];
  const int*   ei  = (const int*)d_in[1];   // [2][E]: src = ei, dst = ei + NE
  const float* W   = (const float*)d_in[2];
  const float* a_l = (const float*)d_in[3];
  const float* a_r = (const float*)d_in[4];
  float* out = (float*)d_out;

  const int* src = ei;
  const int* dst = ei + NE;

  // workspace layout (4-byte words; every array 16B-aligned)
  unsigned int* Whh = (unsigned int*)d_ws;            // NN*64 words (12.8 MB)
  float* e_l4     = (float*)(Whh + (size_t)NN * 64);  // NN*4
  float* e_r4     = e_l4 + NN * NH;                   // NN*4
  unsigned short* Btf = (unsigned short*)(e_r4 + NN * NH); // 36 KB
  unsigned int* ebuf = (unsigned int*)(Btf + 9 * 4 * 64 * 8); // 98*1563*32 (19.6 MB)
  (void)ws_size; (void)in_sizes; (void)n_in; (void)out_size;

  k_prep<<<BCOLS, 128, 0, stream>>>(W, a_l, a_r, Btf);

  k_gemm_part<<<GRID1, 256, 0, stream>>>(
      x, Btf, src, dst, ebuf, (unsigned short*)Whh, e_l4, e_r4);

  k_lists_agg<<<NBUK, 256, 0, stream>>>(ebuf, e_l4, e_r4, Whh, out);
}